// Round 3
// baseline (377.514 us; speedup 1.0000x reference)
//
#include <hip/hip_runtime.h>

typedef unsigned short u16;
using bf16x8 = __attribute__((ext_vector_type(8))) short;
using f32x4  = __attribute__((ext_vector_type(4))) float;
using s16x4  = __attribute__((ext_vector_type(4))) short;

#define S_LEN 512
#define D_DIM 128
#define SCALE 0.08838834764831845f   // 1/sqrt(128)

__device__ __forceinline__ u16 f2b(float x) {  // RNE f32 -> bf16
  union { float f; unsigned int i; } v; v.f = x;
  unsigned int u = v.i;
  return (u16)((u + 0x7fffu + ((u >> 16) & 1u)) >> 16);
}
__device__ __forceinline__ bf16x8 pack8(f32x4 a, f32x4 b) {
  bf16x8 r;
  r[0] = (short)f2b(a[0]); r[1] = (short)f2b(a[1]);
  r[2] = (short)f2b(a[2]); r[3] = (short)f2b(a[3]);
  r[4] = (short)f2b(b[0]); r[5] = (short)f2b(b[1]);
  r[6] = (short)f2b(b[2]); r[7] = (short)f2b(b[3]);
  return r;
}

// Inputs fp32, output fp32 (reference dtypes); MFMA operands bf16 in-register.
// Block: 256 threads = 4 waves; wave handles 16 q-rows; block = 64 q-rows of one n.
// S^T = K.Q^T via mfma(A=K, B=Q): lane holds S[q=lane&15][kv=quad*4+reg].
// PV via mfma(A=P-packed, B=VT-from-LDS), k-permutation pi(8Q+j)=4Q+j | 16+4Q+(j-4)
// applied identically on A and B sides.
__global__ __launch_bounds__(256, 2)
void attn_fused(const float* __restrict__ Q, const float* __restrict__ K,
                const float* __restrict__ V, const int* __restrict__ VL,
                const float* __restrict__ WM, float* __restrict__ O) {
  __shared__ short VT[128 * 132];  // VT[d][kv_local] bf16, stride 132, XOR-swizzled kv

  const int bid  = blockIdx.x;
  const int n    = bid >> 3;
  const int qt   = bid & 7;
  const int tid  = threadIdx.x;
  const int wave = tid >> 6;
  const int L    = tid & 63;
  const int quad = L >> 4;
  const int lq   = L & 15;
  const int qw   = qt * 64 + wave * 16;   // wave's q base
  const int qg   = qw + lq;               // this lane's q row (softmax state row)
  const int w    = (n >> 3) & 15;         // window index: n = ((b*16 + w)*8 + h)

  const float* Qn  = Q + (size_t)n * S_LEN * D_DIM;
  const float* Kn  = K + (size_t)n * S_LEN * D_DIM;
  const float* Vn  = V + (size_t)n * S_LEN * D_DIM;
  const float* WMq = WM + ((size_t)w * S_LEN + qg) * S_LEN;

  const int vlen  = VL[n];
  const int kvlim = (vlen == 0) ? S_LEN : vlen;  // vlen==0: uniform softmax over all

  // Q fragments (B-operand): lane holds Q[qg][dc*32 + quad*8 + j], j=0..7
  bf16x8 qf[4];
#pragma unroll
  for (int dc = 0; dc < 4; ++dc) {
    const f32x4* qp = (const f32x4*)(Qn + (size_t)qg * D_DIM + dc * 32 + quad * 8);
    qf[dc] = pack8(qp[0], qp[1]);
  }

  f32x4 o[8];
#pragma unroll
  for (int t = 0; t < 8; ++t) o[t] = (f32x4){0.f, 0.f, 0.f, 0.f};
  float mrun = -1e30f, lrun = 0.f;

  for (int cb = 0; cb < S_LEN; cb += 128) {
    if (cb >= kvlim) break;                 // block-uniform
    __syncthreads();                        // protect VT from previous chunk readers
    // ---- stage V^T chunk (fp32 -> bf16): VT[d][kv] = V[cb+kv][d], kv in [0,128) ----
#pragma unroll
    for (int s = 0; s < 8; ++s) {
      int i  = s * 256 + tid;
      int r  = i >> 4;        // kv_local 0..127
      int cc = i & 15;        // 8-float chunk within row
      const f32x4* vp = (const f32x4*)(Vn + (size_t)(cb + r) * D_DIM + cc * 8);
      f32x4 va = vp[0], vb = vp[1];
      int swz = (cc & 7) << 2;              // XOR swizzle keyed on d>>3 (== cc)
      int col = r ^ swz;
      VT[(cc * 8 + 0) * 132 + col] = (short)f2b(va[0]);
      VT[(cc * 8 + 1) * 132 + col] = (short)f2b(va[1]);
      VT[(cc * 8 + 2) * 132 + col] = (short)f2b(va[2]);
      VT[(cc * 8 + 3) * 132 + col] = (short)f2b(va[3]);
      VT[(cc * 8 + 4) * 132 + col] = (short)f2b(vb[0]);
      VT[(cc * 8 + 5) * 132 + col] = (short)f2b(vb[1]);
      VT[(cc * 8 + 6) * 132 + col] = (short)f2b(vb[2]);
      VT[(cc * 8 + 7) * 132 + col] = (short)f2b(vb[3]);
    }
    __syncthreads();

    for (int ib = 0; ib < 4; ++ib) {
      const int kvb = cb + ib * 32;
      if (kvb >= kvlim) break;
      // ---- S^T: two 16-kv tiles, A = K rows (converted), B = Q frags ----
      f32x4 a0 = {0,0,0,0}, a1 = {0,0,0,0};
      const float* K0 = Kn + (size_t)(kvb + lq) * D_DIM;
      const float* K1 = Kn + (size_t)(kvb + 16 + lq) * D_DIM;
#pragma unroll
      for (int dc = 0; dc < 4; ++dc) {
        const f32x4* k0p = (const f32x4*)(K0 + dc * 32 + quad * 8);
        const f32x4* k1p = (const f32x4*)(K1 + dc * 32 + quad * 8);
        bf16x8 kf0 = pack8(k0p[0], k0p[1]);
        bf16x8 kf1 = pack8(k1p[0], k1p[1]);
        a0 = __builtin_amdgcn_mfma_f32_16x16x32_bf16(kf0, qf[dc], a0, 0, 0, 0);
        a1 = __builtin_amdgcn_mfma_f32_16x16x32_bf16(kf1, qf[dc], a1, 0, 0, 0);
      }
      // ---- scores: scale + window mask (fp32) + valid-len mask (-1e6 like ref) ----
      f32x4 wm0 = *(const f32x4*)(WMq + kvb + quad * 4);
      f32x4 wm1 = *(const f32x4*)(WMq + kvb + 16 + quad * 4);
      float s0[4], s1[4];
      float mloc = -1e30f;
#pragma unroll
      for (int r = 0; r < 4; ++r) {
        int k0i = kvb + quad * 4 + r;
        s0[r] = (k0i < vlen)      ? a0[r] * SCALE + wm0[r] : -1e6f;
        s1[r] = (k0i + 16 < vlen) ? a1[r] * SCALE + wm1[r] : -1e6f;
        mloc = fmaxf(mloc, fmaxf(s0[r], s1[r]));
      }
      // row max across quads (lanes L, L^16, L^32, L^48 share q = lane&15)
      mloc = fmaxf(mloc, __shfl_xor(mloc, 16, 64));
      mloc = fmaxf(mloc, __shfl_xor(mloc, 32, 64));
      const float mnew  = fmaxf(mrun, mloc);
      const float alpha = __expf(mrun - mnew);
      mrun = mnew;

      u16 pu[8];
      float psum = 0.f;
#pragma unroll
      for (int r = 0; r < 4; ++r) {
        union { unsigned int i; float f; } c0, c1;
        u16 u0 = f2b(__expf(s0[r] - mnew));
        u16 u1 = f2b(__expf(s1[r] - mnew));
        pu[r] = u0; pu[4 + r] = u1;
        c0.i = ((unsigned int)u0) << 16; c1.i = ((unsigned int)u1) << 16;
        psum += c0.f + c1.f;                // sum the rounded values for consistency
      }
      psum += __shfl_xor(psum, 16, 64);
      psum += __shfl_xor(psum, 32, 64);
      lrun = lrun * alpha + psum;

      // alpha for O rows (O C-layout row = quad*4+reg; state lives at lane lq==row)
      float ar[4];
#pragma unroll
      for (int r = 0; r < 4; ++r) ar[r] = __shfl(alpha, quad * 4 + r, 64);

      // P A-fragment: [T0 p0..p3 | T1 p0..p3] == pi-permuted k order
      bf16x8 pf;
#pragma unroll
      for (int j = 0; j < 8; ++j) pf[j] = (short)pu[j];

      const int kloc = kvb & 127;
#pragma unroll
      for (int t = 0; t < 8; ++t) {
        int d   = 16 * t + lq;
        int swz = ((d >> 3) & 7) << 2;
        s16x4 b0 = *(const s16x4*)(VT + d * 132 + ((kloc + quad * 4) ^ swz));
        s16x4 b1 = *(const s16x4*)(VT + d * 132 + ((kloc + 16 + quad * 4) ^ swz));
        bf16x8 bv = {b0[0], b0[1], b0[2], b0[3], b1[0], b1[1], b1[2], b1[3]};
        f32x4 ot = o[t];
#pragma unroll
        for (int r = 0; r < 4; ++r) ot[r] *= ar[r];
        o[t] = __builtin_amdgcn_mfma_f32_16x16x32_bf16(pf, bv, ot, 0, 0, 0);
      }
    }
  }

  // ---- epilogue: normalize by l (redistributed to O rows) and store fp32 ----
  float linv[4];
#pragma unroll
  for (int r = 0; r < 4; ++r) {
    float lr = __shfl(lrun, quad * 4 + r, 64);
    linv[r] = 1.f / lr;
  }
  float* On = O + (size_t)n * S_LEN * D_DIM;
#pragma unroll
  for (int t = 0; t < 8; ++t) {
#pragma unroll
    for (int r = 0; r < 4; ++r) {
      On[(size_t)(qw + quad * 4 + r) * D_DIM + 16 * t + lq] = o[t][r] * linv[r];
    }
  }
}

extern "C" void kernel_launch(void* const* d_in, const int* in_sizes, int n_in,
                              void* d_out, int out_size, void* d_ws, size_t ws_size,
                              hipStream_t stream) {
  const float* Q  = (const float*)d_in[0];
  const float* K  = (const float*)d_in[1];
  const float* V  = (const float*)d_in[2];
  const int*   VL = (const int*)d_in[3];
  const float* WM = (const float*)d_in[4];
  float* O = (float*)d_out;
  dim3 grid(256 * 8), block(256);
  attn_fused<<<grid, block, 0, stream>>>(Q, K, V, VL, WM, O);
}

// Round 4
// 345.533 us; speedup vs baseline: 1.0926x; 1.0926x over previous
//
#include <hip/hip_runtime.h>

typedef unsigned short u16;
using bf16x8 = __attribute__((ext_vector_type(8))) short;
using f32x4  = __attribute__((ext_vector_type(4))) float;
using s16x4  = __attribute__((ext_vector_type(4))) short;

#define S_LEN 512
#define D_DIM 128
#define CB    64                     // kv chunk staged in LDS
#define KS    136                    // K LDS stride (shorts): 272B rows, 16B-aligned, bank-uniform b128
#define VS    68                     // VT LDS stride (shorts)
#define SCALE 0.08838834764831845f   // 1/sqrt(128)

__device__ __forceinline__ u16 f2b(float x) {  // RNE f32 -> bf16
  union { float f; unsigned int i; } v; v.f = x;
  unsigned int u = v.i;
  return (u16)((u + 0x7fffu + ((u >> 16) & 1u)) >> 16);
}
__device__ __forceinline__ bf16x8 pack8(f32x4 a, f32x4 b) {
  bf16x8 r;
  r[0] = (short)f2b(a[0]); r[1] = (short)f2b(a[1]);
  r[2] = (short)f2b(a[2]); r[3] = (short)f2b(a[3]);
  r[4] = (short)f2b(b[0]); r[5] = (short)f2b(b[1]);
  r[6] = (short)f2b(b[2]); r[7] = (short)f2b(b[3]);
  return r;
}

// fp32 in / fp32 out. S^T = K.Q^T (A=K from LDS, B=Q regs); PV with pi-permuted
// packing (verified round 3). K+V staged to LDS bf16 once per block per chunk.
// bid remap: n%8 == bid%8 and same-n blocks within a 64-bid window -> same XCD L2.
__global__ __launch_bounds__(256, 4)
void attn_fused(const float* __restrict__ Q, const float* __restrict__ K,
                const float* __restrict__ V, const int* __restrict__ VL,
                const float* __restrict__ WM, float* __restrict__ O) {
  __shared__ short Ksh[CB * KS];     // Ksh[kv_local][d], bf16
  __shared__ short VT[D_DIM * VS];   // VT[d][kv_local], bf16, XOR-swizzled kv

  const int bid  = blockIdx.x;
  const int n    = (bid & 7) | ((bid >> 6) << 3);   // n%8 == bid%8 (XCD)
  const int qt   = (bid >> 3) & 7;
  const int tid  = threadIdx.x;
  const int wave = tid >> 6;
  const int L    = tid & 63;
  const int quad = L >> 4;
  const int lq   = L & 15;
  const int qw   = qt * 64 + wave * 16;   // wave's q base
  const int qg   = qw + lq;               // this lane's q row (softmax state row)
  const int w    = (n >> 3) & 15;         // window index: n = ((b*16 + w)*8 + h)

  const float* Qn  = Q + (size_t)n * S_LEN * D_DIM;
  const float* Kn  = K + (size_t)n * S_LEN * D_DIM;
  const float* Vn  = V + (size_t)n * S_LEN * D_DIM;
  const float* WMq = WM + ((size_t)w * S_LEN + qg) * S_LEN;

  const int vlen  = VL[n];
  const int kvlim = (vlen == 0) ? S_LEN : vlen;  // vlen==0: uniform softmax over all

  // Q fragments (B-operand): lane holds Q[qg][dc*32 + quad*8 + j], j=0..7
  bf16x8 qf[4];
#pragma unroll
  for (int dc = 0; dc < 4; ++dc) {
    const f32x4* qp = (const f32x4*)(Qn + (size_t)qg * D_DIM + dc * 32 + quad * 8);
    qf[dc] = pack8(qp[0], qp[1]);
  }

  f32x4 o[8];
#pragma unroll
  for (int t = 0; t < 8; ++t) o[t] = (f32x4){0.f, 0.f, 0.f, 0.f};
  float mrun = -1e30f, lrun = 0.f;

  for (int cb = 0; cb < S_LEN; cb += CB) {
    if (cb >= kvlim) break;                 // block-uniform
    __syncthreads();                        // protect LDS from previous chunk readers

    // ---- WM prefetch for this chunk (2 tiles x 2 subtiles), overlaps staging ----
    f32x4 wm[4];
#pragma unroll
    for (int j = 0; j < 4; ++j)
      wm[j] = *(const f32x4*)(WMq + cb + j * 16 + quad * 4);

    // ---- stage K (row-major) and V^T (swizzled) chunk, fp32 -> bf16, once per block ----
#pragma unroll
    for (int s = 0; s < 4; ++s) {
      int i  = s * 256 + tid;
      int r  = i >> 4;        // kv_local 0..63
      int cc = i & 15;        // 8-float chunk within row (d-chunk)
      const f32x4* kp = (const f32x4*)(Kn + (size_t)(cb + r) * D_DIM + cc * 8);
      const f32x4* vp = (const f32x4*)(Vn + (size_t)(cb + r) * D_DIM + cc * 8);
      f32x4 ka = kp[0], kb = kp[1];
      f32x4 va = vp[0], vb = vp[1];
      *(bf16x8*)(Ksh + r * KS + cc * 8) = pack8(ka, kb);   // ds_write_b128, bank-uniform
      int col = r ^ ((cc & 7) << 2);                        // swizzle keyed on d>>3 == cc
      short* vt = VT + (cc * 8) * VS + col;
      vt[0 * VS] = (short)f2b(va[0]);
      vt[1 * VS] = (short)f2b(va[1]);
      vt[2 * VS] = (short)f2b(va[2]);
      vt[3 * VS] = (short)f2b(va[3]);
      vt[4 * VS] = (short)f2b(vb[0]);
      vt[5 * VS] = (short)f2b(vb[1]);
      vt[6 * VS] = (short)f2b(vb[2]);
      vt[7 * VS] = (short)f2b(vb[3]);
    }
    __syncthreads();

#pragma unroll
    for (int ib = 0; ib < 2; ++ib) {
      const int kvb = cb + ib * 32;
      if (kvb >= kvlim) break;
      const int kloc = ib * 32;
      // ---- S^T: two 16-kv subtiles, A = K rows from LDS, B = Q frags ----
      f32x4 a0 = {0,0,0,0}, a1 = {0,0,0,0};
#pragma unroll
      for (int dc = 0; dc < 4; ++dc) {
        bf16x8 kf0 = *(const bf16x8*)(Ksh + (kloc + lq) * KS + dc * 32 + quad * 8);
        bf16x8 kf1 = *(const bf16x8*)(Ksh + (kloc + 16 + lq) * KS + dc * 32 + quad * 8);
        a0 = __builtin_amdgcn_mfma_f32_16x16x32_bf16(kf0, qf[dc], a0, 0, 0, 0);
        a1 = __builtin_amdgcn_mfma_f32_16x16x32_bf16(kf1, qf[dc], a1, 0, 0, 0);
      }
      // ---- scores: scale + window mask + valid-len mask (-1e6 like ref) ----
      const f32x4 wm0 = wm[ib * 2], wm1 = wm[ib * 2 + 1];
      float s0[4], s1[4];
      float mloc = -1e30f;
#pragma unroll
      for (int r = 0; r < 4; ++r) {
        int k0i = kvb + quad * 4 + r;
        s0[r] = (k0i < vlen)      ? a0[r] * SCALE + wm0[r] : -1e6f;
        s1[r] = (k0i + 16 < vlen) ? a1[r] * SCALE + wm1[r] : -1e6f;
        mloc = fmaxf(mloc, fmaxf(s0[r], s1[r]));
      }
      // row max across quads (lanes L, L^16, L^32, L^48 share q = lane&15)
      mloc = fmaxf(mloc, __shfl_xor(mloc, 16, 64));
      mloc = fmaxf(mloc, __shfl_xor(mloc, 32, 64));
      const float mnew  = fmaxf(mrun, mloc);
      const float alpha = __expf(mrun - mnew);
      mrun = mnew;

      u16 pu[8];
      float psum = 0.f;
#pragma unroll
      for (int r = 0; r < 4; ++r) {
        union { unsigned int i; float f; } c0, c1;
        u16 u0 = f2b(__expf(s0[r] - mnew));
        u16 u1 = f2b(__expf(s1[r] - mnew));
        pu[r] = u0; pu[4 + r] = u1;
        c0.i = ((unsigned int)u0) << 16; c1.i = ((unsigned int)u1) << 16;
        psum += c0.f + c1.f;                // sum the rounded values for consistency
      }
      psum += __shfl_xor(psum, 16, 64);
      psum += __shfl_xor(psum, 32, 64);
      lrun = lrun * alpha + psum;

      // alpha for O rows (O C-layout row = quad*4+reg; state lives at lane lq==row)
      float ar[4];
#pragma unroll
      for (int r = 0; r < 4; ++r) ar[r] = __shfl(alpha, quad * 4 + r, 64);

      // P A-fragment: [T0 p0..p3 | T1 p0..p3] == pi-permuted k order
      bf16x8 pf;
#pragma unroll
      for (int j = 0; j < 8; ++j) pf[j] = (short)pu[j];

#pragma unroll
      for (int t = 0; t < 8; ++t) {
        int d   = 16 * t + lq;
        int swz = ((d >> 3) & 7) << 2;
        s16x4 b0 = *(const s16x4*)(VT + d * VS + ((kloc + quad * 4) ^ swz));
        s16x4 b1 = *(const s16x4*)(VT + d * VS + ((kloc + 16 + quad * 4) ^ swz));
        bf16x8 bv = {b0[0], b0[1], b0[2], b0[3], b1[0], b1[1], b1[2], b1[3]};
        f32x4 ot = o[t];
#pragma unroll
        for (int r = 0; r < 4; ++r) ot[r] *= ar[r];
        o[t] = __builtin_amdgcn_mfma_f32_16x16x32_bf16(pf, bv, ot, 0, 0, 0);
      }
    }
  }

  // ---- epilogue: normalize by l (redistributed to O rows) and store fp32 ----
  float linv[4];
#pragma unroll
  for (int r = 0; r < 4; ++r) {
    float lr = __shfl(lrun, quad * 4 + r, 64);
    linv[r] = 1.f / lr;
  }
  float* On = O + (size_t)n * S_LEN * D_DIM;
#pragma unroll
  for (int t = 0; t < 8; ++t) {
#pragma unroll
    for (int r = 0; r < 4; ++r) {
      On[(size_t)(qw + quad * 4 + r) * D_DIM + 16 * t + lq] = o[t][r] * linv[r];
    }
  }
}

extern "C" void kernel_launch(void* const* d_in, const int* in_sizes, int n_in,
                              void* d_out, int out_size, void* d_ws, size_t ws_size,
                              hipStream_t stream) {
  const float* Q  = (const float*)d_in[0];
  const float* K  = (const float*)d_in[1];
  const float* V  = (const float*)d_in[2];
  const int*   VL = (const int*)d_in[3];
  const float* WM = (const float*)d_in[4];
  float* O = (float*)d_out;
  dim3 grid(256 * 8), block(256);
  attn_fused<<<grid, block, 0, stream>>>(Q, K, V, VL, WM, O);
}